// Round 2
// 763.584 us; speedup vs baseline: 1.8846x; 1.8846x over previous
//
#include <hip/hip_runtime.h>
#include <stdint.h>

// Swin-V2 window attention, 3-stage pipeline (fp32 I/O, bf16 MFMA compute):
//   1) gemm_qkv : qkv = bf16(x @ Wqkv^T + b), q/k cosine-normalized in epilogue
//   2) attn     : per (window, head) S=qn@kn^T*scale+bias+mask, softmax, O=P@V
//   3) gemm_proj: out = O @ Wproj^T + b (fp32)
// Workspace: [rbias f32 663KB][wqkv bf16 393KB][wproj bf16 131KB][qkv bf16][O bf16]
// Windows are chunked so the dynamic part fits ws_size (CH in {1..128}; every
// chunk keeps WPC%8==0 so M stays a multiple of 128 -> no bounds code anywhere).

typedef __attribute__((ext_vector_type(4))) float floatx4;
typedef __attribute__((ext_vector_type(8))) __bf16 bf16x8;

#define LOGIT_MAX 4.6051701859880914f

__device__ __forceinline__ uint16_t f2bf(float f) {
    union { float f32; uint32_t u; } x;
    x.f32 = f;
    uint32_t r = x.u + 0x7FFFu + ((x.u >> 16) & 1u);  // RNE
    return (uint16_t)(r >> 16);
}

// load 8 consecutive fp32 -> bf16x8 (16B-aligned source)
__device__ __forceinline__ bf16x8 cvt8(const float* __restrict__ p) {
    const floatx4 a = *(const floatx4*)p;
    const floatx4 b = *(const floatx4*)(p + 4);
    union { bf16x8 v; uint16_t u[8]; } r;
    r.u[0] = f2bf(a[0]); r.u[1] = f2bf(a[1]); r.u[2] = f2bf(a[2]); r.u[3] = f2bf(a[3]);
    r.u[4] = f2bf(b[0]); r.u[5] = f2bf(b[1]); r.u[6] = f2bf(b[2]); r.u[7] = f2bf(b[3]);
    return r.v;
}

// async global->LDS, 16B per lane; l must be wave-uniform base (HW adds lane*16)
__device__ __forceinline__ void glds16(const uint16_t* g, uint16_t* l) {
    __builtin_amdgcn_global_load_lds((const __attribute__((address_space(1))) uint32_t*)g,
                                     (__attribute__((address_space(3))) uint32_t*)l, 16, 0, 0);
}

// ---------------------------------------------------------------------------
// prep: qkv_w (768x256) and proj_w (256x256) fp32 -> bf16
// ---------------------------------------------------------------------------
__global__ __launch_bounds__(256) void cvtw_kernel(const float* __restrict__ qkvw,
                                                   const float* __restrict__ projw,
                                                   uint16_t* __restrict__ wqkv,
                                                   uint16_t* __restrict__ wproj) {
    const int i = blockIdx.x * 256 + threadIdx.x;
    if (i < 768 * 256) wqkv[i] = f2bf(qkvw[i]);
    if (i < 256 * 256) wproj[i] = f2bf(projw[i]);
}

// ---------------------------------------------------------------------------
// Relative-position bias via meta MLP: outb[h][p], p = i*144 + j, fp32.
// ---------------------------------------------------------------------------
__global__ __launch_bounds__(256) void rbias_kernel(const float* __restrict__ fc1w,
                                                    const float* __restrict__ fc1b,
                                                    const float* __restrict__ fc2w,
                                                    const float* __restrict__ fc2b,
                                                    float* __restrict__ outb) {
    __shared__ float w1a[384], w1b[384], b1[384];
    __shared__ float w2[8 * 384];
    for (int i = threadIdx.x; i < 384; i += 256) {
        w1a[i] = fc1w[2 * i];
        w1b[i] = fc1w[2 * i + 1];
        b1[i]  = fc1b[i];
    }
    for (int i = threadIdx.x; i < 3072; i += 256) w2[i] = fc2w[i];
    __syncthreads();
    const int p = blockIdx.x * 256 + threadIdx.x;
    if (p >= 144 * 144) return;
    const int i = p / 144;
    const int j = p - i * 144;
    const float dy = (float)(i / 12 - j / 12);
    const float dx = (float)(i % 12 - j % 12);
    const float cy = (dy > 0.f ? 1.f : (dy < 0.f ? -1.f : 0.f)) * log1pf(fabsf(dy));
    const float cx = (dx > 0.f ? 1.f : (dx < 0.f ? -1.f : 0.f)) * log1pf(fabsf(dx));
    float acc[8] = {0, 0, 0, 0, 0, 0, 0, 0};
    for (int t = 0; t < 384; t++) {
        float hv = fmaf(cy, w1a[t], fmaf(cx, w1b[t], b1[t]));
        hv = fmaxf(hv, 0.f);
#pragma unroll
        for (int hh = 0; hh < 8; hh++) acc[hh] = fmaf(hv, w2[hh * 384 + t], acc[hh]);
    }
#pragma unroll
    for (int hh = 0; hh < 8; hh++) outb[(size_t)hh * 20736 + p] = acc[hh] + fc2b[hh];
}

// ---------------------------------------------------------------------------
// GEMM 1: qkv[Mc][768] bf16 = x[Mc][256] @ Wqkv^T + b, q/k rows L2-normalized
// per head (32-col groups) in fp32 before the bf16 rounding.
// 128x128 tile, 4 waves, BK=64, XOR-swizzled LDS (16B slot s ^ (row&7)).
// ---------------------------------------------------------------------------
__global__ __launch_bounds__(256) void gemm_qkv_kernel(const float* __restrict__ x,
                                                       const uint16_t* __restrict__ W,
                                                       const float* __restrict__ bias,
                                                       uint16_t* __restrict__ outq) {
    __shared__ __align__(16) uint16_t sA[8192];  // [128][64] bf16, swizzled
    __shared__ __align__(16) uint16_t sB[8192];
    const int tid  = threadIdx.x;
    const int lane = tid & 63;
    const int w    = tid >> 6;
    const int wr   = (w >> 1) << 6;
    const int wc   = (w & 1) << 6;
    const int lr   = lane & 15;
    const int q4   = lane >> 4;
    const int brow = (blockIdx.x / 6) << 7;
    const int bcol = (blockIdx.x % 6) << 7;

    floatx4 acc[4][4];
#pragma unroll
    for (int m = 0; m < 4; m++)
#pragma unroll
        for (int n = 0; n < 4; n++) acc[m][n] = (floatx4){0.f, 0.f, 0.f, 0.f};

#pragma unroll 1
    for (int ks = 0; ks < 4; ++ks) {
        const int bk = ks << 6;
        __syncthreads();  // previous step's LDS reads done
        // stage A (x fp32 -> bf16, reg path, swizzled write == pre-swizzled src)
#pragma unroll
        for (int i = 0; i < 4; ++i) {
            const int c = (i << 8) + tid;        // LDS 16B-chunk id
            const int r = c >> 3, s = c & 7;
            const int sg = s ^ (r & 7);          // source chunk for this slot
            const bf16x8 v = cvt8(x + (size_t)(brow + r) * 256 + bk + (sg << 3));
            *(bf16x8*)&sA[c << 3] = v;
        }
        // stage B (weights bf16) via global_load_lds, pre-swizzled source
#pragma unroll
        for (int i = 0; i < 4; ++i) {
            const int c = (i << 8) + tid;
            const int r = c >> 3, s = c & 7;
            const int sg = s ^ (r & 7);
            glds16(W + (size_t)(bcol + r) * 256 + bk + (sg << 3),
                   &sB[(size_t)((i << 8) + (w << 6)) << 3]);
        }
        __syncthreads();  // drains vmcnt+lgkmcnt
#pragma unroll
        for (int kk = 0; kk < 2; ++kk) {
            const int cb = (kk << 6) + (q4 << 4);  // byte offset of 16B chunk
            bf16x8 af[4], bfq[4];
#pragma unroll
            for (int m = 0; m < 4; ++m) {
                const int r = wr + (m << 4) + lr;
                af[m] = *(const bf16x8*)((const char*)sA + r * 128 + (cb ^ ((r & 7) << 4)));
            }
#pragma unroll
            for (int n = 0; n < 4; ++n) {
                const int r = wc + (n << 4) + lr;
                bfq[n] = *(const bf16x8*)((const char*)sB + r * 128 + (cb ^ ((r & 7) << 4)));
            }
#pragma unroll
            for (int m = 0; m < 4; ++m)
#pragma unroll
                for (int n = 0; n < 4; ++n)
                    acc[m][n] = __builtin_amdgcn_mfma_f32_16x16x32_bf16(af[m], bfq[n], acc[m][n], 0, 0, 0);
        }
    }
    // bias (before normalization, per reference)
#pragma unroll
    for (int n = 0; n < 4; ++n) {
        const float bb = bias[bcol + wc + (n << 4) + lr];
#pragma unroll
        for (int m = 0; m < 4; ++m)
#pragma unroll
            for (int r = 0; r < 4; ++r) acc[m][n][r] += bb;
    }
    // cosine-normalize q,k rows: 32-col head groups = tile pairs (np, np+1)
    if (bcol < 512) {
#pragma unroll
        for (int m = 0; m < 4; ++m)
#pragma unroll
            for (int np = 0; np < 4; np += 2)
#pragma unroll
                for (int r = 0; r < 4; ++r) {
                    float ss = acc[m][np][r] * acc[m][np][r] + acc[m][np + 1][r] * acc[m][np + 1][r];
#pragma unroll
                    for (int o = 1; o < 16; o <<= 1) ss += __shfl_xor(ss, o, 64);
                    const float rn = 1.0f / fmaxf(sqrtf(ss), 1e-12f);
                    acc[m][np][r] *= rn;
                    acc[m][np + 1][r] *= rn;
                }
    }
    // store bf16: C-layout col = lr, row = q4*4 + r
#pragma unroll
    for (int m = 0; m < 4; ++m)
#pragma unroll
        for (int r = 0; r < 4; ++r) {
            const size_t row = (size_t)(brow + wr + (m << 4) + (q4 << 2) + r);
#pragma unroll
            for (int n = 0; n < 4; ++n)
                outq[row * 768 + bcol + wc + (n << 4) + lr] = f2bf(acc[m][n][r]);
        }
}

// ---------------------------------------------------------------------------
// Attention per (window, head): 9 waves x 16-row bands. 3 barriers total.
// LDS (uint16): qn[144][40] kn[144][40] (overlaid by PB[144][168]) | vT[32][168]
// Strides: 40 elem = 20 dwords, 168 elem = 84 dwords -> 2-way bank alias = free.
// ---------------------------------------------------------------------------
__global__ __launch_bounds__(576, 2) void attn_kernel(const uint16_t* __restrict__ qkv,
                                                      const float* __restrict__ mask,
                                                      const float* __restrict__ rbias,
                                                      const float* __restrict__ lsc,
                                                      uint16_t* __restrict__ ob,
                                                      const int win_base) {
    __shared__ __align__(16) uint16_t sm[29568];  // 59.1 KB
    uint16_t* const PB = sm;            // [144][168], overlays qn/kn
    uint16_t* const qn = sm;            // [144][40]
    uint16_t* const kn = sm + 5760;     // [144][40]
    uint16_t* const vT = sm + 24192;    // [32][168], cols 144..167 zero

    const int wl   = blockIdx.x >> 3;
    const int h    = blockIdx.x & 7;
    const int tid  = threadIdx.x;
    const int lane = tid & 63;
    const int mi   = tid >> 6;          // band 0..8
    const int lr   = lane & 15;
    const int kq   = (lane >> 4) << 3;
    const int rq   = (lane >> 4) << 2;
    const int arow = mi * 16 + lr;

    // ---- stage qn, kn (padded stride 40) and v transposed into vT ----
    {
        const int l  = tid >> 2;            // 0..143
        const int d0 = (tid & 3) << 3;      // 0,8,16,24
        const uint16_t* base = qkv + (size_t)(wl * 144 + l) * 768 + h * 32 + d0;
        *(bf16x8*)&qn[l * 40 + d0] = *(const bf16x8*)(base);
        *(bf16x8*)&kn[l * 40 + d0] = *(const bf16x8*)(base + 256);
        union { bf16x8 v; uint16_t u[8]; } vv;
        vv.v = *(const bf16x8*)(base + 512);
#pragma unroll
        for (int u = 0; u < 8; ++u) vT[(d0 + u) * 168 + l] = vv.u[u];
        for (int i = tid; i < 32 * 24; i += 576) vT[(i / 24) * 168 + 144 + (i % 24)] = 0;
    }
    __syncthreads();  // B1: qn/kn/vT ready

    // ---- S = qn @ kn^T * scale + rbias + mask ----
    const float scale = __expf(fminf(lsc[h], LOGIT_MAX));
    const float* bh = rbias + (size_t)h * 20736;
    const float* mw = mask + (size_t)((win_base + wl) & 63) * 20736;
    const bf16x8 aq = *(const bf16x8*)&qn[arow * 40 + kq];
    float sl[9][4];
#pragma unroll
    for (int ni = 0; ni < 9; ni++) {
        const bf16x8 bkf = *(const bf16x8*)&kn[(ni * 16 + lr) * 40 + kq];
        floatx4 s = (floatx4){0.f, 0.f, 0.f, 0.f};
        s = __builtin_amdgcn_mfma_f32_16x16x32_bf16(aq, bkf, s, 0, 0, 0);
#pragma unroll
        for (int r = 0; r < 4; r++) {
            const int row = mi * 16 + rq + r;
            const int col = ni * 16 + lr;
            sl[ni][r] = s[r] * scale + bh[row * 144 + col] + mw[row * 144 + col];
        }
    }
    // ---- softmax over 144 cols (16-lane reduce) ----
#pragma unroll
    for (int r = 0; r < 4; r++) {
        float m = -3.0e38f;
#pragma unroll
        for (int ni = 0; ni < 9; ni++) m = fmaxf(m, sl[ni][r]);
#pragma unroll
        for (int o = 1; o < 16; o <<= 1) m = fmaxf(m, __shfl_xor(m, o, 64));
        float s = 0.f;
#pragma unroll
        for (int ni = 0; ni < 9; ni++) {
            float e = __expf(sl[ni][r] - m);
            sl[ni][r] = e;
            s += e;
        }
#pragma unroll
        for (int o = 1; o < 16; o <<= 1) s += __shfl_xor(s, o, 64);
        const float inv = 1.0f / s;
#pragma unroll
        for (int ni = 0; ni < 9; ni++) sl[ni][r] *= inv;
    }
    __syncthreads();  // B2: qn/kn reads done before PB overlays them

    // ---- P -> PB [144][168] bf16, pad cols zeroed ----
#pragma unroll
    for (int ni = 0; ni < 9; ni++)
#pragma unroll
        for (int r = 0; r < 4; r++)
            PB[(mi * 16 + rq + r) * 168 + ni * 16 + lr] = f2bf(sl[ni][r]);
#pragma unroll
    for (int u = 0; u < 6; ++u) {
        const int idx = u * 64 + lane;  // 0..383 = 16 rows x 24 pad cols
        PB[(mi * 16 + (idx / 24)) * 168 + 144 + (idx % 24)] = 0;
    }
    __syncthreads();  // B3: P ready

    // ---- O band = P[band] @ V (K=160 over 5 steps, 2 d-tiles) ----
    floatx4 o0 = (floatx4){0.f, 0.f, 0.f, 0.f};
    floatx4 o1 = (floatx4){0.f, 0.f, 0.f, 0.f};
#pragma unroll
    for (int kt = 0; kt < 5; kt++) {
        const bf16x8 pa = *(const bf16x8*)&PB[arow * 168 + kt * 32 + kq];
        const bf16x8 v0 = *(const bf16x8*)&vT[lr * 168 + kt * 32 + kq];
        const bf16x8 v1 = *(const bf16x8*)&vT[(16 + lr) * 168 + kt * 32 + kq];
        o0 = __builtin_amdgcn_mfma_f32_16x16x32_bf16(pa, v0, o0, 0, 0, 0);
        o1 = __builtin_amdgcn_mfma_f32_16x16x32_bf16(pa, v1, o1, 0, 0, 0);
    }
    // ---- write O bf16 into proj-GEMM A-operand layout [Mc][256] ----
#pragma unroll
    for (int r = 0; r < 4; r++) {
        const size_t row = (size_t)wl * 144 + mi * 16 + rq + r;
        ob[row * 256 + h * 32 + lr]      = f2bf(o0[r]);
        ob[row * 256 + h * 32 + 16 + lr] = f2bf(o1[r]);
    }
}

// ---------------------------------------------------------------------------
// GEMM 2: out[Mc][256] fp32 = O[Mc][256] bf16 @ Wproj^T + b. Same structure.
// ---------------------------------------------------------------------------
__global__ __launch_bounds__(256) void gemm_proj_kernel(const uint16_t* __restrict__ A,
                                                        const uint16_t* __restrict__ W,
                                                        const float* __restrict__ bias,
                                                        float* __restrict__ outp) {
    __shared__ __align__(16) uint16_t sA[8192];
    __shared__ __align__(16) uint16_t sB[8192];
    const int tid  = threadIdx.x;
    const int lane = tid & 63;
    const int w    = tid >> 6;
    const int wr   = (w >> 1) << 6;
    const int wc   = (w & 1) << 6;
    const int lr   = lane & 15;
    const int q4   = lane >> 4;
    const int brow = (blockIdx.x >> 1) << 7;
    const int bcol = (blockIdx.x & 1) << 7;

    floatx4 acc[4][4];
#pragma unroll
    for (int m = 0; m < 4; m++)
#pragma unroll
        for (int n = 0; n < 4; n++) acc[m][n] = (floatx4){0.f, 0.f, 0.f, 0.f};

#pragma unroll 1
    for (int ks = 0; ks < 4; ++ks) {
        const int bk = ks << 6;
        __syncthreads();
#pragma unroll
        for (int i = 0; i < 4; ++i) {
            const int c = (i << 8) + tid;
            const int r = c >> 3, s = c & 7;
            const int sg = s ^ (r & 7);
            glds16(A + (size_t)(brow + r) * 256 + bk + (sg << 3),
                   &sA[(size_t)((i << 8) + (w << 6)) << 3]);
        }
#pragma unroll
        for (int i = 0; i < 4; ++i) {
            const int c = (i << 8) + tid;
            const int r = c >> 3, s = c & 7;
            const int sg = s ^ (r & 7);
            glds16(W + (size_t)(bcol + r) * 256 + bk + (sg << 3),
                   &sB[(size_t)((i << 8) + (w << 6)) << 3]);
        }
        __syncthreads();
#pragma unroll
        for (int kk = 0; kk < 2; ++kk) {
            const int cb = (kk << 6) + (q4 << 4);
            bf16x8 af[4], bfq[4];
#pragma unroll
            for (int m = 0; m < 4; ++m) {
                const int r = wr + (m << 4) + lr;
                af[m] = *(const bf16x8*)((const char*)sA + r * 128 + (cb ^ ((r & 7) << 4)));
            }
#pragma unroll
            for (int n = 0; n < 4; ++n) {
                const int r = wc + (n << 4) + lr;
                bfq[n] = *(const bf16x8*)((const char*)sB + r * 128 + (cb ^ ((r & 7) << 4)));
            }
#pragma unroll
            for (int m = 0; m < 4; ++m)
#pragma unroll
                for (int n = 0; n < 4; ++n)
                    acc[m][n] = __builtin_amdgcn_mfma_f32_16x16x32_bf16(af[m], bfq[n], acc[m][n], 0, 0, 0);
        }
    }
#pragma unroll
    for (int n = 0; n < 4; ++n) {
        const float bb = bias[bcol + wc + (n << 4) + lr];
#pragma unroll
        for (int m = 0; m < 4; ++m)
#pragma unroll
            for (int r = 0; r < 4; ++r) {
                const size_t row = (size_t)(brow + wr + (m << 4) + (q4 << 2) + r);
                outp[row * 256 + bcol + wc + (n << 4) + lr] = acc[m][n][r] + bb;
            }
    }
}

// ---------------------------------------------------------------------------
extern "C" void kernel_launch(void* const* d_in, const int* in_sizes, int n_in,
                              void* d_out, int out_size, void* d_ws, size_t ws_size,
                              hipStream_t stream) {
    (void)in_sizes; (void)n_in; (void)out_size;
    const float* x      = (const float*)d_in[0];
    const float* mask   = (const float*)d_in[1];
    const float* qkv_w  = (const float*)d_in[2];
    const float* qkv_b  = (const float*)d_in[3];
    const float* proj_w = (const float*)d_in[4];
    const float* proj_b = (const float*)d_in[5];
    const float* fc1_w  = (const float*)d_in[6];
    const float* fc1_b  = (const float*)d_in[7];
    const float* fc2_w  = (const float*)d_in[8];
    const float* fc2_b  = (const float*)d_in[9];
    const float* lsc    = (const float*)d_in[10];
    float* out = (float*)d_out;

    float* bias_ws  = (float*)d_ws;                   // 165888 f32 = 663 KB
    uint16_t* wqkv  = (uint16_t*)(bias_ws + 165888);  // 196608 bf16
    uint16_t* wproj = wqkv + 196608;                  // 65536 bf16
    uint16_t* dyn   = wproj + 65536;                  // byte offset 1,187,840

    // chunk windows so [qkv bf16][O bf16] = WPC*144*2048 B fits ws_size.
    // WPC = 1024/CH stays a multiple of 8 => MC % 128 == 0.
    int CH = 1;
    while (CH < 128) {
        const size_t need = 1187840ULL + ((size_t)(1024 / CH) * 144) * 2048ULL;
        if (need <= ws_size) break;
        CH <<= 1;
    }
    const int WPC = 1024 / CH;       // windows per chunk (>= 8)
    const int MC  = WPC * 144;       // rows per chunk (multiple of 128)
    uint16_t* qkvws = dyn;                        // [MC][768] bf16
    uint16_t* obws  = dyn + (size_t)MC * 768;     // [MC][256] bf16

    cvtw_kernel<<<768, 256, 0, stream>>>(qkv_w, proj_w, wqkv, wproj);
    rbias_kernel<<<81, 256, 0, stream>>>(fc1_w, fc1_b, fc2_w, fc2_b, bias_ws);
    for (int c = 0; c < CH; ++c) {
        const float* xc = x + (size_t)c * MC * 256;
        gemm_qkv_kernel<<<(MC / 128) * 6, 256, 0, stream>>>(xc, wqkv, qkv_b, qkvws);
        attn_kernel<<<WPC * 8, 576, 0, stream>>>(qkvws, mask, bias_ws, lsc, obws, c * WPC);
        gemm_proj_kernel<<<(MC / 128) * 2, 256, 0, stream>>>(obws, wproj, proj_b,
                                                             out + (size_t)c * MC * 256);
    }
}

// Round 4
// 704.409 us; speedup vs baseline: 2.0429x; 1.0840x over previous
//
#include <hip/hip_runtime.h>
#include <stdint.h>

// Swin-V2 window attention, 4-stage pipeline (fp32 I/O, bf16 MFMA compute):
//   0) cvtx     : x fp32 -> bf16 (read once)
//   1) gemm_qkv : qkv = bf16(x @ Wqkv^T + b), q/k cosine-normalized in epilogue
//   2) attn     : block = (mask-slice, head), loops G windows sharing the slice;
//                 bias+mask stay L2-hot via XCD-aware block swizzle
//   3) gemm_proj: out = O @ Wproj^T + b (fp32)
// (Resubmit of round-3 source: audited clean; prior failure diagnosed as infra.)

typedef __attribute__((ext_vector_type(4))) float floatx4;
typedef __attribute__((ext_vector_type(8))) __bf16 bf16x8;

#define LOGIT_MAX 4.6051701859880914f
#define LOG2E 1.4426950408889634f

__device__ __forceinline__ uint16_t f2bf(float f) {
    union { float f32; uint32_t u; } x;
    x.f32 = f;
    uint32_t r = x.u + 0x7FFFu + ((x.u >> 16) & 1u);  // RNE
    return (uint16_t)(r >> 16);
}

// load 8 consecutive fp32 -> bf16x8 (16B-aligned source)
__device__ __forceinline__ bf16x8 cvt8(const float* __restrict__ p) {
    const floatx4 a = *(const floatx4*)p;
    const floatx4 b = *(const floatx4*)(p + 4);
    union { bf16x8 v; uint16_t u[8]; } r;
    r.u[0] = f2bf(a[0]); r.u[1] = f2bf(a[1]); r.u[2] = f2bf(a[2]); r.u[3] = f2bf(a[3]);
    r.u[4] = f2bf(b[0]); r.u[5] = f2bf(b[1]); r.u[6] = f2bf(b[2]); r.u[7] = f2bf(b[3]);
    return r.v;
}

// async global->LDS, 16B per lane; l must be wave-uniform base (HW adds lane*16)
__device__ __forceinline__ void glds16(const uint16_t* g, uint16_t* l) {
    __builtin_amdgcn_global_load_lds((const __attribute__((address_space(1))) uint32_t*)g,
                                     (__attribute__((address_space(3))) uint32_t*)l, 16, 0, 0);
}

// ---------------------------------------------------------------------------
// prep: qkv_w (768x256) and proj_w (256x256) fp32 -> bf16
// ---------------------------------------------------------------------------
__global__ __launch_bounds__(256) void cvtw_kernel(const float* __restrict__ qkvw,
                                                   const float* __restrict__ projw,
                                                   uint16_t* __restrict__ wqkv,
                                                   uint16_t* __restrict__ wproj) {
    const int i = blockIdx.x * 256 + threadIdx.x;
    if (i < 768 * 256) wqkv[i] = f2bf(qkvw[i]);
    if (i < 256 * 256) wproj[i] = f2bf(projw[i]);
}

// ---------------------------------------------------------------------------
// prep: x fp32 -> bf16, 8 elems/thread (grid sized exactly: n % 2048 == 0)
// ---------------------------------------------------------------------------
__global__ __launch_bounds__(256) void cvtx_kernel(const float* __restrict__ x,
                                                   uint16_t* __restrict__ xb) {
    const size_t i = (size_t)blockIdx.x * 256 + threadIdx.x;
    *(bf16x8*)(xb + i * 8) = cvt8(x + i * 8);
}

// ---------------------------------------------------------------------------
// Relative-position bias via meta MLP: outb[h][p], p = i*144 + j, fp32.
// ---------------------------------------------------------------------------
__global__ __launch_bounds__(256) void rbias_kernel(const float* __restrict__ fc1w,
                                                    const float* __restrict__ fc1b,
                                                    const float* __restrict__ fc2w,
                                                    const float* __restrict__ fc2b,
                                                    float* __restrict__ outb) {
    __shared__ float w1a[384], w1b[384], b1[384];
    __shared__ float w2[8 * 384];
    for (int i = threadIdx.x; i < 384; i += 256) {
        w1a[i] = fc1w[2 * i];
        w1b[i] = fc1w[2 * i + 1];
        b1[i]  = fc1b[i];
    }
    for (int i = threadIdx.x; i < 3072; i += 256) w2[i] = fc2w[i];
    __syncthreads();
    const int p = blockIdx.x * 256 + threadIdx.x;
    if (p >= 144 * 144) return;
    const int i = p / 144;
    const int j = p - i * 144;
    const float dy = (float)(i / 12 - j / 12);
    const float dx = (float)(i % 12 - j % 12);
    const float cy = (dy > 0.f ? 1.f : (dy < 0.f ? -1.f : 0.f)) * log1pf(fabsf(dy));
    const float cx = (dx > 0.f ? 1.f : (dx < 0.f ? -1.f : 0.f)) * log1pf(fabsf(dx));
    float acc[8] = {0, 0, 0, 0, 0, 0, 0, 0};
    for (int t = 0; t < 384; t++) {
        float hv = fmaf(cy, w1a[t], fmaf(cx, w1b[t], b1[t]));
        hv = fmaxf(hv, 0.f);
#pragma unroll
        for (int hh = 0; hh < 8; hh++) acc[hh] = fmaf(hv, w2[hh * 384 + t], acc[hh]);
    }
#pragma unroll
    for (int hh = 0; hh < 8; hh++) outb[(size_t)hh * 20736 + p] = acc[hh] + fc2b[hh];
}

// ---------------------------------------------------------------------------
// GEMM 1: qkv[Mc][768] bf16 = xb[Mc][256] @ Wqkv^T + b, q/k rows L2-normalized
// per head (32-col groups) in fp32 before the bf16 rounding.
// 128x128 tile, 4 waves, BK=64, XOR-swizzled LDS, both operands via glds16.
// XCD swizzle: contiguous row-panels per XCD (A slab + B stay L2-hot).
// ---------------------------------------------------------------------------
__global__ __launch_bounds__(256) void gemm_qkv_kernel(const uint16_t* __restrict__ xb,
                                                       const uint16_t* __restrict__ W,
                                                       const float* __restrict__ bias,
                                                       uint16_t* __restrict__ outq) {
    __shared__ __align__(16) uint16_t sA[8192];  // [128][64] bf16, swizzled
    __shared__ __align__(16) uint16_t sB[8192];
    const int tid  = threadIdx.x;
    const int lane = tid & 63;
    const int w    = tid >> 6;
    const int wr   = (w >> 1) << 6;
    const int wc   = (w & 1) << 6;
    const int lr   = lane & 15;
    const int q4   = lane >> 4;
    int bid = blockIdx.x;
    if ((gridDim.x & 7) == 0) {  // XCD-aware: XCD j owns a contiguous panel range
        const int per = gridDim.x >> 3;
        bid = (bid & 7) * per + (bid >> 3);
    }
    const int brow = (bid / 6) << 7;
    const int bcol = (bid % 6) << 7;

    floatx4 acc[4][4];
#pragma unroll
    for (int m = 0; m < 4; m++)
#pragma unroll
        for (int n = 0; n < 4; n++) acc[m][n] = (floatx4){0.f, 0.f, 0.f, 0.f};

#pragma unroll 1
    for (int ks = 0; ks < 4; ++ks) {
        const int bk = ks << 6;
        __syncthreads();  // previous step's LDS reads done
#pragma unroll
        for (int i = 0; i < 4; ++i) {
            const int c = (i << 8) + tid;        // LDS 16B-chunk id
            const int r = c >> 3, s = c & 7;
            const int sg = s ^ (r & 7);          // source chunk for this slot
            glds16(xb + (size_t)(brow + r) * 256 + bk + (sg << 3),
                   &sA[(size_t)((i << 8) + (w << 6)) << 3]);
        }
#pragma unroll
        for (int i = 0; i < 4; ++i) {
            const int c = (i << 8) + tid;
            const int r = c >> 3, s = c & 7;
            const int sg = s ^ (r & 7);
            glds16(W + (size_t)(bcol + r) * 256 + bk + (sg << 3),
                   &sB[(size_t)((i << 8) + (w << 6)) << 3]);
        }
        __syncthreads();  // drains vmcnt+lgkmcnt
#pragma unroll
        for (int kk = 0; kk < 2; ++kk) {
            const int cb = (kk << 6) + (q4 << 4);  // byte offset of 16B chunk
            bf16x8 af[4], bfq[4];
#pragma unroll
            for (int m = 0; m < 4; ++m) {
                const int r = wr + (m << 4) + lr;
                af[m] = *(const bf16x8*)((const char*)sA + r * 128 + (cb ^ ((r & 7) << 4)));
            }
#pragma unroll
            for (int n = 0; n < 4; ++n) {
                const int r = wc + (n << 4) + lr;
                bfq[n] = *(const bf16x8*)((const char*)sB + r * 128 + (cb ^ ((r & 7) << 4)));
            }
#pragma unroll
            for (int m = 0; m < 4; ++m)
#pragma unroll
                for (int n = 0; n < 4; ++n)
                    acc[m][n] = __builtin_amdgcn_mfma_f32_16x16x32_bf16(af[m], bfq[n], acc[m][n], 0, 0, 0);
        }
    }
    // bias (before normalization, per reference)
#pragma unroll
    for (int n = 0; n < 4; ++n) {
        const float bb = bias[bcol + wc + (n << 4) + lr];
#pragma unroll
        for (int m = 0; m < 4; ++m)
#pragma unroll
            for (int r = 0; r < 4; ++r) acc[m][n][r] += bb;
    }
    // cosine-normalize q,k rows: 32-col head groups = tile pairs (np, np+1)
    if (bcol < 512) {
#pragma unroll
        for (int m = 0; m < 4; ++m)
#pragma unroll
            for (int np = 0; np < 4; np += 2)
#pragma unroll
                for (int r = 0; r < 4; ++r) {
                    float ss = acc[m][np][r] * acc[m][np][r] + acc[m][np + 1][r] * acc[m][np + 1][r];
#pragma unroll
                    for (int o = 1; o < 16; o <<= 1) ss += __shfl_xor(ss, o, 64);
                    const float rn = 1.0f / fmaxf(sqrtf(ss), 1e-12f);
                    acc[m][np][r] *= rn;
                    acc[m][np + 1][r] *= rn;
                }
    }
    // store bf16: C-layout col = lr, row = q4*4 + r
#pragma unroll
    for (int m = 0; m < 4; ++m)
#pragma unroll
        for (int r = 0; r < 4; ++r) {
            const size_t row = (size_t)(brow + wr + (m << 4) + (q4 << 2) + r);
#pragma unroll
            for (int n = 0; n < 4; ++n)
                outq[row * 768 + bcol + wc + (n << 4) + lr] = f2bf(acc[m][n][r]);
        }
}

// ---------------------------------------------------------------------------
// Attention: block = (slice s4, head h); loops G windows wl = s4 + 64*t (all
// share mask slice (win_base+s4)&63). 9 waves x 16-row bands, 4 barriers/window.
// XCD swizzle keeps per-XCD table working set at 1.33 MB (L2-hot re-reads).
// LDS (uint16): qn[144][40] kn[144][40] (overlaid by PB[144][168]) | vT[32][168]
// ---------------------------------------------------------------------------
__global__ __launch_bounds__(576, 2) void attn_kernel(const uint16_t* __restrict__ qkv,
                                                      const float* __restrict__ mask,
                                                      const float* __restrict__ rbias,
                                                      const float* __restrict__ lsc,
                                                      uint16_t* __restrict__ ob,
                                                      const int win_base, const int G) {
    __shared__ __align__(16) uint16_t sm[29568];  // 59.1 KB
    uint16_t* const PB = sm;            // [144][168], overlays qn/kn
    uint16_t* const qn = sm;            // [144][40]
    uint16_t* const kn = sm + 5760;     // [144][40]
    uint16_t* const vT = sm + 24192;    // [32][168], cols 144..167 zero

    int bid = blockIdx.x;
    if ((gridDim.x & 7) == 0) {  // XCD j gets slices [8j, 8j+8) x all heads
        const int per = gridDim.x >> 3;
        bid = (bid & 7) * per + (bid >> 3);
    }
    const int s4   = bid >> 3;          // slice
    const int h    = bid & 7;
    const int tid  = threadIdx.x;
    const int lane = tid & 63;
    const int mi   = tid >> 6;          // band 0..8
    const int lr   = lane & 15;
    const int kq   = (lane >> 4) << 3;
    const int rq   = (lane >> 4) << 2;
    const int arow = mi * 16 + lr;

    const float scale2 = __expf(fminf(lsc[h], LOGIT_MAX)) * LOG2E;
    const float* bh = rbias + (size_t)h * 20736;
    const float* mw = mask + (size_t)((win_base + s4) & 63) * 20736;

    const int l   = tid >> 2;           // 0..143 (staging row)
    const int d0  = (tid & 3) << 3;     // 0,8,16,24 (staging d-offset)
    const int rot = d0 >> 3;            // rotation so d0-groups hit distinct banks

    // zero vT pad cols once (never overwritten)
    for (int i = tid; i < 32 * 24; i += 576) vT[(i / 24) * 168 + 144 + (i % 24)] = 0;

    // prefetch window 0 q/k/v fragments
    const uint16_t* base0 = qkv + ((size_t)s4 * 144 + l) * 768 + h * 32 + d0;
    bf16x8 pq = *(const bf16x8*)(base0);
    bf16x8 pk = *(const bf16x8*)(base0 + 256);
    bf16x8 pv = *(const bf16x8*)(base0 + 512);

#pragma unroll 1
    for (int t = 0; t < G; ++t) {
        // ---- stage current window from prefetch regs ----
        *(bf16x8*)&qn[l * 40 + d0] = pq;
        *(bf16x8*)&kn[l * 40 + d0] = pk;
        {
            union { bf16x8 v; uint16_t u[8]; } vv;
            vv.v = pv;
#pragma unroll
            for (int u = 0; u < 8; ++u) {
                const int rr = (u + rot) & 7;   // rotated row order: spreads banks
                vT[(d0 + rr) * 168 + l] = vv.u[rr];
            }
        }
        __syncthreads();  // B1: qn/kn/vT ready

        // ---- issue prefetch for window t+1 (hidden under QK+softmax) ----
        if (t + 1 < G) {
            const uint16_t* base = qkv + ((size_t)(s4 + ((t + 1) << 6)) * 144 + l) * 768 + h * 32 + d0;
            pq = *(const bf16x8*)(base);
            pk = *(const bf16x8*)(base + 256);
            pv = *(const bf16x8*)(base + 512);
        }

        // ---- S2 = qn @ kn^T * scale2 + (bias+mask)*log2e  (exp2 domain) ----
        const bf16x8 aq = *(const bf16x8*)&qn[arow * 40 + kq];
        float sl[9][4];
#pragma unroll
        for (int ni = 0; ni < 9; ni++) {
            const bf16x8 bkf = *(const bf16x8*)&kn[(ni * 16 + lr) * 40 + kq];
            floatx4 s = (floatx4){0.f, 0.f, 0.f, 0.f};
            s = __builtin_amdgcn_mfma_f32_16x16x32_bf16(aq, bkf, s, 0, 0, 0);
#pragma unroll
            for (int r = 0; r < 4; r++) {
                const int row = mi * 16 + rq + r;
                const int col = ni * 16 + lr;
                sl[ni][r] = fmaf(s[r], scale2, (bh[row * 144 + col] + mw[row * 144 + col]) * LOG2E);
            }
        }
        // ---- softmax over 144 cols (16-lane reduce, base-2) ----
#pragma unroll
        for (int r = 0; r < 4; r++) {
            float m = -3.0e38f;
#pragma unroll
            for (int ni = 0; ni < 9; ni++) m = fmaxf(m, sl[ni][r]);
#pragma unroll
            for (int o = 1; o < 16; o <<= 1) m = fmaxf(m, __shfl_xor(m, o, 64));
            float s = 0.f;
#pragma unroll
            for (int ni = 0; ni < 9; ni++) {
                float e = exp2f(sl[ni][r] - m);
                sl[ni][r] = e;
                s += e;
            }
#pragma unroll
            for (int o = 1; o < 16; o <<= 1) s += __shfl_xor(s, o, 64);
            const float inv = 1.0f / s;
#pragma unroll
            for (int ni = 0; ni < 9; ni++) sl[ni][r] *= inv;
        }
        __syncthreads();  // B2: qn/kn reads done before PB overlays them

        // ---- P -> PB [144][168] bf16, pad cols re-zeroed (staging clobbers) ----
#pragma unroll
        for (int ni = 0; ni < 9; ni++)
#pragma unroll
            for (int r = 0; r < 4; r++)
                PB[(mi * 16 + rq + r) * 168 + ni * 16 + lr] = f2bf(sl[ni][r]);
#pragma unroll
        for (int u = 0; u < 6; ++u) {
            const int idx = u * 64 + lane;  // 16 rows x 24 pad cols per band
            PB[(mi * 16 + (idx / 24)) * 168 + 144 + (idx % 24)] = 0;
        }
        __syncthreads();  // B3: P ready

        // ---- O band = P[band] @ V (K=160 over 5 steps, 2 d-tiles) ----
        floatx4 o0 = (floatx4){0.f, 0.f, 0.f, 0.f};
        floatx4 o1 = (floatx4){0.f, 0.f, 0.f, 0.f};
#pragma unroll
        for (int kt = 0; kt < 5; kt++) {
            const bf16x8 pa = *(const bf16x8*)&PB[arow * 168 + kt * 32 + kq];
            const bf16x8 v0 = *(const bf16x8*)&vT[lr * 168 + kt * 32 + kq];
            const bf16x8 v1 = *(const bf16x8*)&vT[(16 + lr) * 168 + kt * 32 + kq];
            o0 = __builtin_amdgcn_mfma_f32_16x16x32_bf16(pa, v0, o0, 0, 0, 0);
            o1 = __builtin_amdgcn_mfma_f32_16x16x32_bf16(pa, v1, o1, 0, 0, 0);
        }
        // ---- write O bf16 into proj-GEMM A-operand layout [Mc][256] ----
#pragma unroll
        for (int r = 0; r < 4; r++) {
            const size_t row = ((size_t)s4 + ((size_t)t << 6)) * 144 + mi * 16 + rq + r;
            ob[row * 256 + h * 32 + lr]      = f2bf(o0[r]);
            ob[row * 256 + h * 32 + 16 + lr] = f2bf(o1[r]);
        }
        __syncthreads();  // B4: PB/vT reads done before next window's staging
    }
}

// ---------------------------------------------------------------------------
// GEMM 2: out[Mc][256] fp32 = O[Mc][256] bf16 @ Wproj^T + b. Same structure.
// ---------------------------------------------------------------------------
__global__ __launch_bounds__(256) void gemm_proj_kernel(const uint16_t* __restrict__ A,
                                                        const uint16_t* __restrict__ W,
                                                        const float* __restrict__ bias,
                                                        float* __restrict__ outp) {
    __shared__ __align__(16) uint16_t sA[8192];
    __shared__ __align__(16) uint16_t sB[8192];
    const int tid  = threadIdx.x;
    const int lane = tid & 63;
    const int w    = tid >> 6;
    const int wr   = (w >> 1) << 6;
    const int wc   = (w & 1) << 6;
    const int lr   = lane & 15;
    const int q4   = lane >> 4;
    int bid = blockIdx.x;
    if ((gridDim.x & 7) == 0) {
        const int per = gridDim.x >> 3;
        bid = (bid & 7) * per + (bid >> 3);
    }
    const int brow = (bid >> 1) << 7;
    const int bcol = (bid & 1) << 7;

    floatx4 acc[4][4];
#pragma unroll
    for (int m = 0; m < 4; m++)
#pragma unroll
        for (int n = 0; n < 4; n++) acc[m][n] = (floatx4){0.f, 0.f, 0.f, 0.f};

#pragma unroll 1
    for (int ks = 0; ks < 4; ++ks) {
        const int bk = ks << 6;
        __syncthreads();
#pragma unroll
        for (int i = 0; i < 4; ++i) {
            const int c = (i << 8) + tid;
            const int r = c >> 3, s = c & 7;
            const int sg = s ^ (r & 7);
            glds16(A + (size_t)(brow + r) * 256 + bk + (sg << 3),
                   &sA[(size_t)((i << 8) + (w << 6)) << 3]);
        }
#pragma unroll
        for (int i = 0; i < 4; ++i) {
            const int c = (i << 8) + tid;
            const int r = c >> 3, s = c & 7;
            const int sg = s ^ (r & 7);
            glds16(W + (size_t)(bcol + r) * 256 + bk + (sg << 3),
                   &sB[(size_t)((i << 8) + (w << 6)) << 3]);
        }
        __syncthreads();
#pragma unroll
        for (int kk = 0; kk < 2; ++kk) {
            const int cb = (kk << 6) + (q4 << 4);
            bf16x8 af[4], bfq[4];
#pragma unroll
            for (int m = 0; m < 4; ++m) {
                const int r = wr + (m << 4) + lr;
                af[m] = *(const bf16x8*)((const char*)sA + r * 128 + (cb ^ ((r & 7) << 4)));
            }
#pragma unroll
            for (int n = 0; n < 4; ++n) {
                const int r = wc + (n << 4) + lr;
                bfq[n] = *(const bf16x8*)((const char*)sB + r * 128 + (cb ^ ((r & 7) << 4)));
            }
#pragma unroll
            for (int m = 0; m < 4; ++m)
#pragma unroll
                for (int n = 0; n < 4; ++n)
                    acc[m][n] = __builtin_amdgcn_mfma_f32_16x16x32_bf16(af[m], bfq[n], acc[m][n], 0, 0, 0);
        }
    }
#pragma unroll
    for (int n = 0; n < 4; ++n) {
        const float bb = bias[bcol + wc + (n << 4) + lr];
#pragma unroll
        for (int m = 0; m < 4; ++m)
#pragma unroll
            for (int r = 0; r < 4; ++r) {
                const size_t row = (size_t)(brow + wr + (m << 4) + (q4 << 2) + r);
                outp[row * 256 + bcol + wc + (n << 4) + lr] = acc[m][n][r] + bb;
            }
    }
}

// ---------------------------------------------------------------------------
extern "C" void kernel_launch(void* const* d_in, const int* in_sizes, int n_in,
                              void* d_out, int out_size, void* d_ws, size_t ws_size,
                              hipStream_t stream) {
    (void)in_sizes; (void)n_in; (void)out_size;
    const float* x      = (const float*)d_in[0];
    const float* mask   = (const float*)d_in[1];
    const float* qkv_w  = (const float*)d_in[2];
    const float* qkv_b  = (const float*)d_in[3];
    const float* proj_w = (const float*)d_in[4];
    const float* proj_b = (const float*)d_in[5];
    const float* fc1_w  = (const float*)d_in[6];
    const float* fc1_b  = (const float*)d_in[7];
    const float* fc2_w  = (const float*)d_in[8];
    const float* fc2_b  = (const float*)d_in[9];
    const float* lsc    = (const float*)d_in[10];
    float* out = (float*)d_out;

    float* bias_ws  = (float*)d_ws;                   // 165888 f32 = 663 KB
    uint16_t* wqkv  = (uint16_t*)(bias_ws + 165888);  // 196608 bf16
    uint16_t* wproj = wqkv + 196608;                  // 65536 bf16
    uint16_t* dyn   = wproj + 65536;                  // byte offset 1,187,840

    // chunk windows so [xb][qkv][ob] bf16 = MC*2560 B fits ws_size.
    // WPC = 1024/CH stays a multiple of 8 => MC % 128 == 0.
    int CH = 1;
    while (CH < 128) {
        const size_t need = 1187840ULL + ((size_t)(1024 / CH) * 144) * 2560ULL;
        if (need <= ws_size) break;
        CH <<= 1;
    }
    const int WPC = 1024 / CH;       // windows per chunk (>= 8)
    const int MC  = WPC * 144;       // rows per chunk (multiple of 128)
    uint16_t* xbws  = dyn;                        // [MC][256] bf16
    uint16_t* qkvws = xbws + (size_t)MC * 256;    // [MC][768] bf16
    uint16_t* obws  = qkvws + (size_t)MC * 768;   // [MC][256] bf16

    const int S_att = (WPC >= 64) ? 64 : WPC;     // mask slices per chunk
    const int G     = WPC / S_att;                // windows per attn block

    cvtw_kernel<<<768, 256, 0, stream>>>(qkv_w, proj_w, wqkv, wproj);
    rbias_kernel<<<81, 256, 0, stream>>>(fc1_w, fc1_b, fc2_w, fc2_b, bias_ws);
    for (int c = 0; c < CH; ++c) {
        cvtx_kernel<<<MC / 8, 256, 0, stream>>>(x + (size_t)c * MC * 256, xbws);
        gemm_qkv_kernel<<<(MC / 128) * 6, 256, 0, stream>>>(xbws, wqkv, qkv_b, qkvws);
        attn_kernel<<<S_att * 8, 576, 0, stream>>>(qkvws, mask, bias_ws, lsc, obws,
                                                   c * WPC, G);
        gemm_proj_kernel<<<(MC / 128) * 2, 256, 0, stream>>>(obws, wproj, proj_b,
                                                             out + (size_t)c * MC * 256);
    }
}

// Round 5
// 662.194 us; speedup vs baseline: 2.1732x; 1.0638x over previous
//
#include <hip/hip_runtime.h>
#include <stdint.h>

// Swin-V2 window attention, 4-stage pipeline (fp32 I/O, bf16 MFMA compute):
//   0) cvtx     : x fp32 -> bf16 (read once)
//   1) gemm_qkv : qkv = bf16(x @ Wqkv^T + b), q/k cosine-normalized in epilogue
//                 2-phase double-buffered (BK=32), 1 barrier per K-step
//   2) attn     : block = (mask-slice, head), loops G windows; bias+mask hoisted
//                 into registers (loop-invariant); deferred 1/sum scaling
//   3) gemm_proj: out = O @ Wproj^T + b (fp32), same 2-phase structure

typedef __attribute__((ext_vector_type(4))) float floatx4;
typedef __attribute__((ext_vector_type(8))) __bf16 bf16x8;

#define LOGIT_MAX 4.6051701859880914f
#define LOG2E 1.4426950408889634f

__device__ __forceinline__ uint16_t f2bf(float f) {
    union { float f32; uint32_t u; } x;
    x.f32 = f;
    uint32_t r = x.u + 0x7FFFu + ((x.u >> 16) & 1u);  // RNE
    return (uint16_t)(r >> 16);
}

__device__ __forceinline__ float bf_lo(uint32_t u) {
    union { uint32_t v; float f; } x; x.v = u << 16; return x.f;
}
__device__ __forceinline__ float bf_hi(uint32_t u) {
    union { uint32_t v; float f; } x; x.v = u & 0xffff0000u; return x.f;
}

// load 8 consecutive fp32 -> bf16x8 (16B-aligned source)
__device__ __forceinline__ bf16x8 cvt8(const float* __restrict__ p) {
    const floatx4 a = *(const floatx4*)p;
    const floatx4 b = *(const floatx4*)(p + 4);
    union { bf16x8 v; uint16_t u[8]; } r;
    r.u[0] = f2bf(a[0]); r.u[1] = f2bf(a[1]); r.u[2] = f2bf(a[2]); r.u[3] = f2bf(a[3]);
    r.u[4] = f2bf(b[0]); r.u[5] = f2bf(b[1]); r.u[6] = f2bf(b[2]); r.u[7] = f2bf(b[3]);
    return r.v;
}

// async global->LDS, 16B per lane; l must be wave-uniform base (HW adds lane*16)
__device__ __forceinline__ void glds16(const uint16_t* g, uint16_t* l) {
    __builtin_amdgcn_global_load_lds((const __attribute__((address_space(1))) uint32_t*)g,
                                     (__attribute__((address_space(3))) uint32_t*)l, 16, 0, 0);
}

// stage one 128x32 bf16 tile pair (A,B) into LDS, swizzled: LDS[r][s] holds
// global chunk s ^ ((r>>1)&3) of row r (16B chunks, 4 per row). 2 chunks/thread.
__device__ __forceinline__ void stage2(const uint16_t* __restrict__ gA,
                                       const uint16_t* __restrict__ gB,
                                       uint16_t* bufA, uint16_t* bufB,
                                       const int tid, const int w) {
#pragma unroll
    for (int i = 0; i < 2; ++i) {
        const int c = (i << 8) + tid;            // chunk id 0..511
        const int r = c >> 2;
        const int sg = (c & 3) ^ ((r >> 1) & 3); // pre-swizzled source chunk
        uint16_t* const dA = bufA + (((i << 8) + (w << 6)) << 3);  // wave-uniform
        uint16_t* const dB = bufB + (((i << 8) + (w << 6)) << 3);
        glds16(gA + (size_t)r * 256 + (sg << 3), dA);
        glds16(gB + (size_t)r * 256 + (sg << 3), dB);
    }
}

// ---------------------------------------------------------------------------
// prep: qkv_w (768x256) and proj_w (256x256) fp32 -> bf16
// ---------------------------------------------------------------------------
__global__ __launch_bounds__(256) void cvtw_kernel(const float* __restrict__ qkvw,
                                                   const float* __restrict__ projw,
                                                   uint16_t* __restrict__ wqkv,
                                                   uint16_t* __restrict__ wproj) {
    const int i = blockIdx.x * 256 + threadIdx.x;
    if (i < 768 * 256) wqkv[i] = f2bf(qkvw[i]);
    if (i < 256 * 256) wproj[i] = f2bf(projw[i]);
}

// ---------------------------------------------------------------------------
// prep: x fp32 -> bf16, 8 elems/thread
// ---------------------------------------------------------------------------
__global__ __launch_bounds__(256) void cvtx_kernel(const float* __restrict__ x,
                                                   uint16_t* __restrict__ xb) {
    const size_t i = (size_t)blockIdx.x * 256 + threadIdx.x;
    *(bf16x8*)(xb + i * 8) = cvt8(x + i * 8);
}

// ---------------------------------------------------------------------------
// Relative-position bias via meta MLP: outb[h][p], p = i*144 + j, fp32.
// ---------------------------------------------------------------------------
__global__ __launch_bounds__(256) void rbias_kernel(const float* __restrict__ fc1w,
                                                    const float* __restrict__ fc1b,
                                                    const float* __restrict__ fc2w,
                                                    const float* __restrict__ fc2b,
                                                    float* __restrict__ outb) {
    __shared__ float w1a[384], w1b[384], b1[384];
    __shared__ float w2[8 * 384];
    for (int i = threadIdx.x; i < 384; i += 256) {
        w1a[i] = fc1w[2 * i];
        w1b[i] = fc1w[2 * i + 1];
        b1[i]  = fc1b[i];
    }
    for (int i = threadIdx.x; i < 3072; i += 256) w2[i] = fc2w[i];
    __syncthreads();
    const int p = blockIdx.x * 256 + threadIdx.x;
    if (p >= 144 * 144) return;
    const int i = p / 144;
    const int j = p - i * 144;
    const float dy = (float)(i / 12 - j / 12);
    const float dx = (float)(i % 12 - j % 12);
    const float cy = (dy > 0.f ? 1.f : (dy < 0.f ? -1.f : 0.f)) * log1pf(fabsf(dy));
    const float cx = (dx > 0.f ? 1.f : (dx < 0.f ? -1.f : 0.f)) * log1pf(fabsf(dx));
    float acc[8] = {0, 0, 0, 0, 0, 0, 0, 0};
    for (int t = 0; t < 384; t++) {
        float hv = fmaf(cy, w1a[t], fmaf(cx, w1b[t], b1[t]));
        hv = fmaxf(hv, 0.f);
#pragma unroll
        for (int hh = 0; hh < 8; hh++) acc[hh] = fmaf(hv, w2[hh * 384 + t], acc[hh]);
    }
#pragma unroll
    for (int hh = 0; hh < 8; hh++) outb[(size_t)hh * 20736 + p] = acc[hh] + fc2b[hh];
}

// ---------------------------------------------------------------------------
// GEMM 1: qkv[Mc][768] bf16 = xb[Mc][256] @ Wqkv^T + b, q/k rows L2-normalized
// per head. 128x128 tile, 4 waves, BK=32, 2-phase double-buffered LDS (32 KB),
// one barrier per K-step; prefetch hidden under MFMA.
// ---------------------------------------------------------------------------
__global__ __launch_bounds__(256) void gemm_qkv_kernel(const uint16_t* __restrict__ xb,
                                                       const uint16_t* __restrict__ W,
                                                       const float* __restrict__ bias,
                                                       uint16_t* __restrict__ outq) {
    __shared__ __align__(16) uint16_t sA[2][4096];  // [128][32] bf16, swizzled
    __shared__ __align__(16) uint16_t sB[2][4096];
    const int tid  = threadIdx.x;
    const int lane = tid & 63;
    const int w    = tid >> 6;
    const int wr   = (w >> 1) << 6;
    const int wc   = (w & 1) << 6;
    const int lr   = lane & 15;
    const int q4   = lane >> 4;
    int bid = blockIdx.x;
    if ((gridDim.x & 7) == 0) {  // XCD-aware: XCD j owns a contiguous panel range
        const int per = gridDim.x >> 3;
        bid = (bid & 7) * per + (bid >> 3);
    }
    const int brow = (bid / 6) << 7;
    const int bcol = (bid % 6) << 7;
    const uint16_t* const gA = xb + (size_t)brow * 256;
    const uint16_t* const gB = W + (size_t)bcol * 256;

    floatx4 acc[4][4];
#pragma unroll
    for (int m = 0; m < 4; m++)
#pragma unroll
        for (int n = 0; n < 4; n++) acc[m][n] = (floatx4){0.f, 0.f, 0.f, 0.f};

    stage2(gA, gB, sA[0], sB[0], tid, w);
    __syncthreads();  // prologue drain
    int cur = 0;
#pragma unroll 1
    for (int ks = 0; ks < 8; ++ks) {
        if (ks < 7) stage2(gA + ((ks + 1) << 5), gB + ((ks + 1) << 5),
                           sA[cur ^ 1], sB[cur ^ 1], tid, w);
        bf16x8 af[4], bfq[4];
#pragma unroll
        for (int m = 0; m < 4; ++m) {
            const int r = wr + (m << 4) + lr;
            af[m] = *(const bf16x8*)((const char*)sA[cur] + r * 64 + ((q4 ^ ((r >> 1) & 3)) << 4));
        }
#pragma unroll
        for (int n = 0; n < 4; ++n) {
            const int r = wc + (n << 4) + lr;
            bfq[n] = *(const bf16x8*)((const char*)sB[cur] + r * 64 + ((q4 ^ ((r >> 1) & 3)) << 4));
        }
#pragma unroll
        for (int m = 0; m < 4; ++m)
#pragma unroll
            for (int n = 0; n < 4; ++n)
                acc[m][n] = __builtin_amdgcn_mfma_f32_16x16x32_bf16(af[m], bfq[n], acc[m][n], 0, 0, 0);
        __syncthreads();  // drains vmcnt(0): next buffer ready, this buffer's reads done
        cur ^= 1;
    }
    // bias (before normalization, per reference)
#pragma unroll
    for (int n = 0; n < 4; ++n) {
        const float bb = bias[bcol + wc + (n << 4) + lr];
#pragma unroll
        for (int m = 0; m < 4; ++m)
#pragma unroll
            for (int r = 0; r < 4; ++r) acc[m][n][r] += bb;
    }
    // cosine-normalize q,k rows: 32-col head groups = tile pairs (np, np+1)
    if (bcol < 512) {
#pragma unroll
        for (int m = 0; m < 4; ++m)
#pragma unroll
            for (int np = 0; np < 4; np += 2)
#pragma unroll
                for (int r = 0; r < 4; ++r) {
                    float ss = acc[m][np][r] * acc[m][np][r] + acc[m][np + 1][r] * acc[m][np + 1][r];
#pragma unroll
                    for (int o = 1; o < 16; o <<= 1) ss += __shfl_xor(ss, o, 64);
                    const float rn = 1.0f / fmaxf(sqrtf(ss), 1e-12f);
                    acc[m][np][r] *= rn;
                    acc[m][np + 1][r] *= rn;
                }
    }
    // store bf16: C-layout col = lr, row = q4*4 + r
#pragma unroll
    for (int m = 0; m < 4; ++m)
#pragma unroll
        for (int r = 0; r < 4; ++r) {
            const size_t row = (size_t)(brow + wr + (m << 4) + (q4 << 2) + r);
#pragma unroll
            for (int n = 0; n < 4; ++n)
                outq[row * 768 + bcol + wc + (n << 4) + lr] = f2bf(acc[m][n][r]);
        }
}

// ---------------------------------------------------------------------------
// Attention: block = (slice s4, head h); loops G windows wl = s4 + 64*t.
// bias+mask hoisted to 18 packed-bf16 VGPRs (loop-invariant); 1/sum deferred
// to the PV output. 9 waves x 16-row bands, 4 barriers/window.
// LDS (uint16): qn[144][40] kn[144][40] (overlaid by PB[144][168]) | vT[32][168]
// ---------------------------------------------------------------------------
__global__ __launch_bounds__(576, 2) void attn_kernel(const uint16_t* __restrict__ qkv,
                                                      const float* __restrict__ mask,
                                                      const float* __restrict__ rbias,
                                                      const float* __restrict__ lsc,
                                                      uint16_t* __restrict__ ob,
                                                      const int win_base, const int G) {
    __shared__ __align__(16) uint16_t sm[29568];  // 59.1 KB
    uint16_t* const PB = sm;            // [144][168], overlays qn/kn
    uint16_t* const qn = sm;            // [144][40]
    uint16_t* const kn = sm + 5760;     // [144][40]
    uint16_t* const vT = sm + 24192;    // [32][168], cols 144..167 zero

    int bid = blockIdx.x;
    if ((gridDim.x & 7) == 0) {  // XCD j gets slices [8j, 8j+8) x all heads
        const int per = gridDim.x >> 3;
        bid = (bid & 7) * per + (bid >> 3);
    }
    const int s4   = bid >> 3;          // slice
    const int h    = bid & 7;
    const int tid  = threadIdx.x;
    const int lane = tid & 63;
    const int mi   = tid >> 6;          // band 0..8
    const int lr   = lane & 15;
    const int kq   = (lane >> 4) << 3;
    const int rq   = (lane >> 4) << 2;
    const int arow = mi * 16 + lr;

    const float scale2 = __expf(fminf(lsc[h], LOGIT_MAX)) * LOG2E;
    const float* bh = rbias + (size_t)h * 20736;
    const float* mw = mask + (size_t)((win_base + s4) & 63) * 20736;

    // hoist (bias+mask)*log2e -> packed bf16 pairs (t-invariant, 18 VGPRs)
    uint32_t bmp[9][2];
#pragma unroll
    for (int ni = 0; ni < 9; ni++)
#pragma unroll
        for (int rp = 0; rp < 2; rp++) {
            const int row0 = mi * 16 + rq + rp * 2;
            const int col  = ni * 16 + lr;
            const float v0 = (bh[row0 * 144 + col] + mw[row0 * 144 + col]) * LOG2E;
            const float v1 = (bh[(row0 + 1) * 144 + col] + mw[(row0 + 1) * 144 + col]) * LOG2E;
            bmp[ni][rp] = (uint32_t)f2bf(v0) | ((uint32_t)f2bf(v1) << 16);
        }

    const int l   = tid >> 2;           // 0..143 (staging row)
    const int d0  = (tid & 3) << 3;     // 0,8,16,24 (staging d-offset)
    const int rot = d0 >> 3;            // rotation so d0-groups hit distinct banks

    // zero vT pad cols once (never overwritten)
    for (int i = tid; i < 32 * 24; i += 576) vT[(i / 24) * 168 + 144 + (i % 24)] = 0;

    // prefetch window 0 q/k/v fragments
    const uint16_t* base0 = qkv + ((size_t)s4 * 144 + l) * 768 + h * 32 + d0;
    bf16x8 pq = *(const bf16x8*)(base0);
    bf16x8 pk = *(const bf16x8*)(base0 + 256);
    bf16x8 pv = *(const bf16x8*)(base0 + 512);

#pragma unroll 1
    for (int t = 0; t < G; ++t) {
        // ---- stage current window from prefetch regs ----
        *(bf16x8*)&qn[l * 40 + d0] = pq;
        *(bf16x8*)&kn[l * 40 + d0] = pk;
        {
            union { bf16x8 v; uint16_t u[8]; } vv;
            vv.v = pv;
#pragma unroll
            for (int u = 0; u < 8; ++u) {
                const int rr = (u + rot) & 7;   // rotated row order: spreads banks
                vT[(d0 + rr) * 168 + l] = vv.u[rr];
            }
        }
        __syncthreads();  // B1: qn/kn/vT ready

        // ---- issue prefetch for window t+1 (hidden under QK+softmax) ----
        if (t + 1 < G) {
            const uint16_t* base = qkv + ((size_t)(s4 + ((t + 1) << 6)) * 144 + l) * 768 + h * 32 + d0;
            pq = *(const bf16x8*)(base);
            pk = *(const bf16x8*)(base + 256);
            pv = *(const bf16x8*)(base + 512);
        }

        // ---- S2 = qn @ kn^T * scale2 + hoisted (bias+mask)*log2e ----
        const bf16x8 aq = *(const bf16x8*)&qn[arow * 40 + kq];
        float sl[9][4];
#pragma unroll
        for (int ni = 0; ni < 9; ni++) {
            const bf16x8 bkf = *(const bf16x8*)&kn[(ni * 16 + lr) * 40 + kq];
            floatx4 s = (floatx4){0.f, 0.f, 0.f, 0.f};
            s = __builtin_amdgcn_mfma_f32_16x16x32_bf16(aq, bkf, s, 0, 0, 0);
            sl[ni][0] = fmaf(s[0], scale2, bf_lo(bmp[ni][0]));
            sl[ni][1] = fmaf(s[1], scale2, bf_hi(bmp[ni][0]));
            sl[ni][2] = fmaf(s[2], scale2, bf_lo(bmp[ni][1]));
            sl[ni][3] = fmaf(s[3], scale2, bf_hi(bmp[ni][1]));
        }
        // ---- softmax over 144 cols (16-lane reduce, base-2, deferred 1/sum) ----
        float invr[4];
#pragma unroll
        for (int r = 0; r < 4; r++) {
            float m = -3.0e38f;
#pragma unroll
            for (int ni = 0; ni < 9; ni++) m = fmaxf(m, sl[ni][r]);
#pragma unroll
            for (int o = 1; o < 16; o <<= 1) m = fmaxf(m, __shfl_xor(m, o, 64));
            float s = 0.f;
#pragma unroll
            for (int ni = 0; ni < 9; ni++) {
                float e = exp2f(sl[ni][r] - m);
                sl[ni][r] = e;
                s += e;
            }
#pragma unroll
            for (int o = 1; o < 16; o <<= 1) s += __shfl_xor(s, o, 64);
            invr[r] = 1.0f / s;
        }
        __syncthreads();  // B2: qn/kn reads done before PB overlays them

        // ---- P (un-normalized) -> PB [144][168] bf16 ----
#pragma unroll
        for (int ni = 0; ni < 9; ni++)
#pragma unroll
            for (int r = 0; r < 4; r++)
                PB[(mi * 16 + rq + r) * 168 + ni * 16 + lr] = f2bf(sl[ni][r]);
        if (t == 0 || mi <= 4) {  // pad cols: only rows<69 clobbered by staging
#pragma unroll
            for (int u = 0; u < 6; ++u) {
                const int idx = u * 64 + lane;
                PB[(mi * 16 + (idx / 24)) * 168 + 144 + (idx % 24)] = 0;
            }
        }
        __syncthreads();  // B3: P ready

        // ---- O band = P[band] @ V (K=160 over 5 steps, 2 d-tiles) ----
        floatx4 o0 = (floatx4){0.f, 0.f, 0.f, 0.f};
        floatx4 o1 = (floatx4){0.f, 0.f, 0.f, 0.f};
#pragma unroll
        for (int kt = 0; kt < 5; kt++) {
            const bf16x8 pa = *(const bf16x8*)&PB[arow * 168 + kt * 32 + kq];
            const bf16x8 v0 = *(const bf16x8*)&vT[lr * 168 + kt * 32 + kq];
            const bf16x8 v1 = *(const bf16x8*)&vT[(16 + lr) * 168 + kt * 32 + kq];
            o0 = __builtin_amdgcn_mfma_f32_16x16x32_bf16(pa, v0, o0, 0, 0, 0);
            o1 = __builtin_amdgcn_mfma_f32_16x16x32_bf16(pa, v1, o1, 0, 0, 0);
        }
        // ---- write O bf16 (deferred softmax normalization applied here) ----
#pragma unroll
        for (int r = 0; r < 4; r++) {
            const size_t row = ((size_t)s4 + ((size_t)t << 6)) * 144 + mi * 16 + rq + r;
            ob[row * 256 + h * 32 + lr]      = f2bf(o0[r] * invr[r]);
            ob[row * 256 + h * 32 + 16 + lr] = f2bf(o1[r] * invr[r]);
        }
        __syncthreads();  // B4: PB/vT reads done before next window's staging
    }
}

// ---------------------------------------------------------------------------
// GEMM 2: out[Mc][256] fp32 = O[Mc][256] bf16 @ Wproj^T + b. 2-phase dbuf.
// ---------------------------------------------------------------------------
__global__ __launch_bounds__(256) void gemm_proj_kernel(const uint16_t* __restrict__ A,
                                                        const uint16_t* __restrict__ W,
                                                        const float* __restrict__ bias,
                                                        float* __restrict__ outp) {
    __shared__ __align__(16) uint16_t sA[2][4096];
    __shared__ __align__(16) uint16_t sB[2][4096];
    const int tid  = threadIdx.x;
    const int lane = tid & 63;
    const int w    = tid >> 6;
    const int wr   = (w >> 1) << 6;
    const int wc   = (w & 1) << 6;
    const int lr   = lane & 15;
    const int q4   = lane >> 4;
    int bid = blockIdx.x;
    if ((gridDim.x & 7) == 0) {
        const int per = gridDim.x >> 3;
        bid = (bid & 7) * per + (bid >> 3);
    }
    const int brow = (bid >> 1) << 7;
    const int bcol = (bid & 1) << 7;
    const uint16_t* const gA = A + (size_t)brow * 256;
    const uint16_t* const gB = W + (size_t)bcol * 256;

    floatx4 acc[4][4];
#pragma unroll
    for (int m = 0; m < 4; m++)
#pragma unroll
        for (int n = 0; n < 4; n++) acc[m][n] = (floatx4){0.f, 0.f, 0.f, 0.f};

    stage2(gA, gB, sA[0], sB[0], tid, w);
    __syncthreads();
    int cur = 0;
#pragma unroll 1
    for (int ks = 0; ks < 8; ++ks) {
        if (ks < 7) stage2(gA + ((ks + 1) << 5), gB + ((ks + 1) << 5),
                           sA[cur ^ 1], sB[cur ^ 1], tid, w);
        bf16x8 af[4], bfq[4];
#pragma unroll
        for (int m = 0; m < 4; ++m) {
            const int r = wr + (m << 4) + lr;
            af[m] = *(const bf16x8*)((const char*)sA[cur] + r * 64 + ((q4 ^ ((r >> 1) & 3)) << 4));
        }
#pragma unroll
        for (int n = 0; n < 4; ++n) {
            const int r = wc + (n << 4) + lr;
            bfq[n] = *(const bf16x8*)((const char*)sB[cur] + r * 64 + ((q4 ^ ((r >> 1) & 3)) << 4));
        }
#pragma unroll
        for (int m = 0; m < 4; ++m)
#pragma unroll
            for (int n = 0; n < 4; ++n)
                acc[m][n] = __builtin_amdgcn_mfma_f32_16x16x32_bf16(af[m], bfq[n], acc[m][n], 0, 0, 0);
        __syncthreads();
        cur ^= 1;
    }
#pragma unroll
    for (int n = 0; n < 4; ++n) {
        const float bb = bias[bcol + wc + (n << 4) + lr];
#pragma unroll
        for (int m = 0; m < 4; ++m)
#pragma unroll
            for (int r = 0; r < 4; ++r) {
                const size_t row = (size_t)(brow + wr + (m << 4) + (q4 << 2) + r);
                outp[row * 256 + bcol + wc + (n << 4) + lr] = acc[m][n][r] + bb;
            }
    }
}

// ---------------------------------------------------------------------------
extern "C" void kernel_launch(void* const* d_in, const int* in_sizes, int n_in,
                              void* d_out, int out_size, void* d_ws, size_t ws_size,
                              hipStream_t stream) {
    (void)in_sizes; (void)n_in; (void)out_size;
    const float* x      = (const float*)d_in[0];
    const float* mask   = (const float*)d_in[1];
    const float* qkv_w  = (const float*)d_in[2];
    const float* qkv_b  = (const float*)d_in[3];
    const float* proj_w = (const float*)d_in[4];
    const float* proj_b = (const float*)d_in[5];
    const float* fc1_w  = (const float*)d_in[6];
    const float* fc1_b  = (const float*)d_in[7];
    const float* fc2_w  = (const float*)d_in[8];
    const float* fc2_b  = (const float*)d_in[9];
    const float* lsc    = (const float*)d_in[10];
    float* out = (float*)d_out;

    float* bias_ws  = (float*)d_ws;                   // 165888 f32 = 663 KB
    uint16_t* wqkv  = (uint16_t*)(bias_ws + 165888);  // 196608 bf16
    uint16_t* wproj = wqkv + 196608;                  // 65536 bf16
    uint16_t* dyn   = wproj + 65536;                  // byte offset 1,187,840

    // chunk windows so [xb][qkv][ob] bf16 = MC*2560 B fits ws_size.
    // WPC = 1024/CH stays a multiple of 8 => MC % 128 == 0.
    int CH = 1;
    while (CH < 128) {
        const size_t need = 1187840ULL + ((size_t)(1024 / CH) * 144) * 2560ULL;
        if (need <= ws_size) break;
        CH <<= 1;
    }
    const int WPC = 1024 / CH;       // windows per chunk (>= 8)
    const int MC  = WPC * 144;       // rows per chunk (multiple of 128)
    uint16_t* xbws  = dyn;                        // [MC][256] bf16
    uint16_t* qkvws = xbws + (size_t)MC * 256;    // [MC][768] bf16
    uint16_t* obws  = qkvws + (size_t)MC * 768;   // [MC][256] bf16

    const int S_att = (WPC >= 64) ? 64 : WPC;     // mask slices per chunk
    const int G     = WPC / S_att;                // windows per attn block

    cvtw_kernel<<<768, 256, 0, stream>>>(qkv_w, proj_w, wqkv, wproj);
    rbias_kernel<<<81, 256, 0, stream>>>(fc1_w, fc1_b, fc2_w, fc2_b, bias_ws);
    for (int c = 0; c < CH; ++c) {
        cvtx_kernel<<<MC / 8, 256, 0, stream>>>(x + (size_t)c * MC * 256, xbws);
        gemm_qkv_kernel<<<(MC / 128) * 6, 256, 0, stream>>>(xbws, wqkv, qkv_b, qkvws);
        attn_kernel<<<S_att * 8, 576, 0, stream>>>(qkvws, mask, bias_ws, lsc, obws,
                                                   c * WPC, G);
        gemm_proj_kernel<<<(MC / 128) * 2, 256, 0, stream>>>(obws, wproj, proj_b,
                                                             out + (size_t)c * MC * 256);
    }
}